// Round 7
// baseline (1280.989 us; speedup 1.0000x reference)
//
#include <hip/hip_runtime.h>
#include <math.h>

#define B_TOT 4096
#define TE 168
#define TD 24
#define NWG 256          // 16 batches per WG; 768 threads -> 3 waves/SIMD
#define HSTR 72          // padded f16 row stride (144 B, 16B-aligned)

typedef _Float16 f16;
typedef __attribute__((ext_vector_type(8))) _Float16 f16x8;
typedef __attribute__((ext_vector_type(4))) float f32x4;

// Activation pre-scaling folded into weights/biases:
//   i,f,o: w *= -log2(e)  -> E = exp2(y) = e^{-x}; sigmoid = 1/(1+E)
//   g:     w *= 2*log2(e) -> E = e^{2x};  tanh = (E-1)/(E+1)
#define SCL_S (-1.4426950408889634f)
#define SCL_G (2.885390081777927f)

// ---------------------------------------------------------------------------
// Pack weights into MFMA B-fragment order, f16, pre-scaled per gate:
//   pk[w][l][q][c][lane][j] = scale_q * Wcomb_l[q*64+w*16+(lane&15)][c*32+(lane>>4)*8+j]
//   l=0 (K=96):  k<8 -> Wih0; 8..31 -> 0; 32..95 -> Whh0[k-32]
//   l=1 (K=128): k<64 -> Wih1 (input h0); else Whh1[k-64] (recurrent h1)
//   l=2 (K=128): k<64 -> Wih2 (input h1); else Whh2[k-64] (recurrent h2)
// ---------------------------------------------------------------------------
__global__ __launch_bounds__(256) void pack_kernel(
    const float* __restrict__ Wih0, const float* __restrict__ Whh0,
    const float* __restrict__ Wih1, const float* __restrict__ Whh1,
    const float* __restrict__ Wih2, const float* __restrict__ Whh2,
    f16* __restrict__ pk)
{
    int idx = blockIdx.x * 256 + threadIdx.x;   // 0 .. 98303
    int j = idx & 7;
    int t = idx >> 3;
    int ln = t & 63; t >>= 6;
    int c  = t & 3;  t >>= 2;
    int q  = t & 3;  t >>= 2;
    int l  = t % 3;
    int w  = t / 3;
    int row = q * 64 + w * 16 + (ln & 15);
    int k   = c * 32 + ((ln >> 4) << 3) + j;
    float val = 0.f;
    if (l == 0) {
        if (k < 8)                 val = Wih0[row * 8 + k];
        else if (k >= 32 && k < 96) val = Whh0[row * 64 + (k - 32)];
    } else if (l == 1) {
        val = (k < 64) ? Wih1[row * 64 + k] : Whh1[row * 64 + (k - 64)];
    } else {
        val = (k < 64) ? Wih2[row * 64 + k] : Whh2[row * 64 + (k - 64)];
    }
    const float sc = (q == 2) ? SCL_G : SCL_S;
    pk[idx] = (f16)(val * sc);
}

__device__ __forceinline__ float softplusf(float x) { return fmaxf(x, 0.f) + log1pf(__expf(-fabsf(x))); }

// ---------------------------------------------------------------------------
// 256 WGs x 768 threads (12 waves); WG owns 16 batches (M=16 tile dense).
// One LAYER per wave role: role = tid>>8 -> 0:L0, 1:L1, 2:L2+staging; within
// a role, wave wv owns hid block wv*16..+16. Per SIMD: one wave of each role
// (round-robin wave->SIMD) = 3 balanced independent issue streams, hiding
// trans latency and stall. Encoder layer-pipelined: round r computes L0(t),
// L1(t-1), L2(t-2); reads parity 1-pp, writes pp; ONE barrier per round.
// Decoder serial (z feedback), phases map 1:1 to roles.
// ---------------------------------------------------------------------------
__global__ __launch_bounds__(768, 3) void lstm_kernel(
    const float* __restrict__ enc_x, const float* __restrict__ enc_z,
    const float* __restrict__ dec_x, const float* __restrict__ v,
    const float* __restrict__ eps,   const f16* __restrict__ pk,
    const float* __restrict__ b0, const float* __restrict__ b1,
    const float* __restrict__ b2,
    const float* __restrict__ w_m, const float* __restrict__ b_m,
    const float* __restrict__ w_a, const float* __restrict__ b_a,
    float* __restrict__ out)
{
    const int tid  = threadIdx.x;
    const int lane = tid & 63;
    const int wv   = (tid >> 6) & 3;    // hid block within role
    const int role = tid >> 8;          // 0:L0, 1:L1, 2:L2+staging
    const int bg   = blockIdx.x * 16;
    const int m16  = lane & 15;
    const int quad = lane >> 4;

    __shared__ f16  hbuf[2][3][16][HSTR];   // [parity][layer][batch][hid]
    __shared__ f16  xbuf[2][16][32];        // [parity][batch][k] (k>=8 stays 0)
    __shared__ float zbuf[16];

    // ---- zero LDS ----
    {
        uint* hz = (uint*)&hbuf[0][0][0][0];
        const int HW = 2 * 3 * 16 * HSTR / 2;   // 3456 words
        for (int i = tid; i < HW; i += 768) hz[i] = 0u;
        uint* xz = (uint*)&xbuf[0][0][0];
        for (int i = tid; i < 512; i += 768) xz[i] = 0u;
    }

    // ---- weight fragments: this wave's layer only ----
    f16x8 wgt[4][4];                    // [chunk][gate]
#define PKOFF(l, q, c) ((((((size_t)wv * 3 + (l)) * 4 + (q)) * 4 + (c)) * 64 + lane) * 8)
    {
        const int nch = (role == 0) ? 3 : 4;
#pragma unroll
        for (int q = 0; q < 4; ++q)
            for (int c = 0; c < nch; ++c)
                wgt[c][q] = *(const f16x8*)(pk + PKOFF(role, q, c));
    }
#undef PKOFF

    const int hid_self = wv * 16 + m16;
    // bias splats (pre-scaled) for this wave's layer; MFMA C operand
    f32x4 bsp[4];
    {
        const float* bp = (role == 0) ? b0 : (role == 1) ? b1 : b2;
#pragma unroll
        for (int q = 0; q < 4; ++q) {
            const float sc = (q == 2) ? SCL_G : SCL_S;
            float bv = bp[q * 64 + hid_self] * sc;
            bsp[q] = (f32x4){bv, bv, bv, bv};
        }
    }

    f16* hb = &hbuf[0][0][0][0];
    const int aoff = m16 * HSTR + quad * 8;
    float cst[4] = {};                  // cell state for this wave's layer

#define HBASE(pp, l) (hb + ((pp) * 3 + (l)) * (16 * HSTR))
#define MFMA16(af, bf, cf) __builtin_amdgcn_mfma_f32_16x16x32_f16(af, bf, cf, 0, 0, 0)

#define MM_F(P, aptr, wi)                                                     \
    {                                                                         \
        f16x8 af = *(const f16x8*)(aptr);                                     \
        P##0 = MFMA16(af, wgt[wi][0], bsp[0]);                                \
        P##1 = MFMA16(af, wgt[wi][1], bsp[1]);                                \
        P##2 = MFMA16(af, wgt[wi][2], bsp[2]);                                \
        P##3 = MFMA16(af, wgt[wi][3], bsp[3]);                                \
    }
#define MM(P, aptr, wi)                                                       \
    {                                                                         \
        f16x8 af = *(const f16x8*)(aptr);                                     \
        P##0 = MFMA16(af, wgt[wi][0], P##0);                                  \
        P##1 = MFMA16(af, wgt[wi][1], P##1);                                  \
        P##2 = MFMA16(af, wgt[wi][2], P##2);                                  \
        P##3 = MFMA16(af, wgt[wi][3], P##3);                                  \
    }

// Merged-rcp cell: sigmoid(f)=pig*R, i*g=(Eg-1)*ef1*R, R=rcp(pig*ef1);
// o*tanh(c)=(Ec-1)*rcp((1+Eo)(1+Ec)). 5 exp2 + 2 rcp per output.
// C/D layout (m89): lane -> col(hid)=m16, rows(batch)=quad*4+r.
#define CELL(P, lh, PP)                                                       \
    {                                                                         \
        f16* hw = HBASE(PP, lh) + hid_self;                                   \
        _Pragma("unroll")                                                     \
        for (int r = 0; r < 4; ++r) {                                         \
            float Ei = __builtin_amdgcn_exp2f(P##0[r]);                       \
            float Ef = __builtin_amdgcn_exp2f(P##1[r]);                       \
            float Eg = __builtin_amdgcn_exp2f(P##2[r]);                       \
            float Eo = __builtin_amdgcn_exp2f(P##3[r]);                       \
            float ef1 = 1.f + Ef;                                             \
            float pig = (1.f + Ei) * (1.f + Eg);                              \
            float R   = __builtin_amdgcn_rcpf(pig * ef1);                     \
            float fv  = pig * R;                                              \
            float ig  = (Eg - 1.f) * ef1 * R;                                 \
            float cn  = fmaf(fv, cst[r], ig);                                 \
            cst[r] = cn;                                                      \
            float Ec  = __builtin_amdgcn_exp2f(cn * SCL_G);                   \
            float Roc = __builtin_amdgcn_rcpf((1.f + Eo) * (1.f + Ec));       \
            hw[(quad * 4 + r) * HSTR] = (f16)((Ec - 1.f) * Roc);              \
        }                                                                     \
    }

    // staging: role-2 threads 512..639 cover 16 batches x 8 k
    const int  sidx = tid - 512;
    const bool isst = (sidx >= 0) && (sidx < 128);
    const int  mS = (sidx >> 3) & 15, kS = sidx & 7;
    const float* xrow = enc_x + ((size_t)(bg + mS) * TE) * 8 + kS;

// One pipelined encoder round, parity PP. role0: L0(t); role1: L1(t-1);
// role2: L2(t-2) + stage x(T0+1) into xbuf[1-PP] (DS), prefetch x(T0+2) (DP).
#define ROUND(PP, D0, D1, D2, DS, DP, T0)                                     \
    {                                                                         \
        __syncthreads();                                                      \
        f32x4 a0, a1, a2, a3;                                                 \
        if (role == 0) {                                                      \
            if (D0) {                                                         \
                MM_F(a, &xbuf[PP][0][0] + m16 * 32 + quad * 8, 0);            \
                MM(a, HBASE(1 - (PP), 0) + aoff,      1);                     \
                MM(a, HBASE(1 - (PP), 0) + aoff + 32, 2);                     \
                CELL(a, 0, PP);                                               \
            }                                                                 \
        } else if (role == 1) {                                               \
            if (D1) {                                                         \
                MM_F(a, HBASE(1 - (PP), 0) + aoff,      0);                   \
                MM(a, HBASE(1 - (PP), 0) + aoff + 32, 1);                     \
                MM(a, HBASE(1 - (PP), 1) + aoff,      2);                     \
                MM(a, HBASE(1 - (PP), 1) + aoff + 32, 3);                     \
                CELL(a, 1, PP);                                               \
            }                                                                 \
        } else {                                                              \
            if (D2) {                                                         \
                MM_F(a, HBASE(1 - (PP), 1) + aoff,      0);                   \
                MM(a, HBASE(1 - (PP), 1) + aoff + 32, 1);                     \
                MM(a, HBASE(1 - (PP), 2) + aoff,      2);                     \
                MM(a, HBASE(1 - (PP), 2) + aoff + 32, 3);                     \
            }                                                                 \
            if (DS && isst) {                                                 \
                xbuf[1 - (PP)][mS][kS] = (f16)xpre;                           \
                if (DP) xpre = xrow[((T0) + 2) * 8];                          \
            }                                                                 \
            if (D2) CELL(a, 2, PP);                                           \
        }                                                                     \
    }

    __syncthreads();   // zero-init visible

    // ---------------- encoder (layer-pipelined) ----------------
    float xpre = 0.f;
    if (isst) {
        xbuf[0][mS][kS] = (f16)xrow[0];
        xpre = xrow[8];
    }
    ROUND(0, 1, 0, 0, 1, 1, 0)           // r=0: L0(0)
    ROUND(1, 1, 1, 0, 1, 1, 1)           // r=1: L0(1), L1(0)
    for (int t = 2; t < 166; t += 2) {   // rounds 2..165 dense
        ROUND(0, 1, 1, 1, 1, 1, t)
        ROUND(1, 1, 1, 1, 1, 1, t + 1)
    }
    ROUND(0, 1, 1, 1, 1, 0, 166)         // r=166: stage x(167), no prefetch
    ROUND(1, 1, 1, 1, 0, 0, 167)         // r=167: last L0
    ROUND(0, 0, 1, 1, 0, 0, 168)         // r=168: L1(167), L2(166)
    ROUND(1, 0, 0, 1, 0, 0, 169)         // r=169: L2(167)
    // exit parities: h0(167)->buf1, h1(167)->buf0, h2(167)->buf1

    // ---------------- decoder (serial; z feedback) ----------------
    const int   mH = (tid >> 4) & 15;     // head batch (role 0, 16 thr each)
    const float vf = (role == 0) ? v[bg + mH] : 0.f;
    float wmr[4], war[4];
#pragma unroll
    for (int r = 0; r < 4; ++r) {
        wmr[r] = w_m[(tid & 15) + 16 * r];
        war[r] = w_a[(tid & 15) + 16 * r];
    }
    const float bmv = b_m[0], bav = b_a[0];
    if (role == 0 && (tid & 15) == 0)
        zbuf[mH] = enc_z[(size_t)(bg + mH) * TE + (TE - 1)] / vf;

// Parities per step t (PA = t&1): L0 reads h0[1-PA] writes h0[PA];
// L1 reads h0[PA]+h1[PA] writes h1[1-PA]; L2 reads h1[1-PA]+h2[1-PA]
// writes h2[PA]; head reads h2[PA]. Matches encoder exit at t=0 (PA=0).
#define DEC_STEP(PA, t)                                                       \
    {                                                                         \
        __syncthreads();  /* zbuf + prev h visible */                         \
        if (isst) {                                                           \
            float xv = (kS == 0) ? zbuf[mS]                                   \
                                 : dec_x[((size_t)(bg + mS) * TD + (t)) * 7 + (kS - 1)]; \
            xbuf[PA][mS][kS] = (f16)xv;                                       \
        }                                                                     \
        __syncthreads();  /* x visible */                                     \
        f32x4 a0, a1, a2, a3;                                                 \
        if (role == 0) {                                                      \
            MM_F(a, &xbuf[PA][0][0] + m16 * 32 + quad * 8, 0);                \
            MM(a, HBASE(1 - (PA), 0) + aoff,      1);                         \
            MM(a, HBASE(1 - (PA), 0) + aoff + 32, 2);                         \
            CELL(a, 0, PA);                                                   \
        }                                                                     \
        __syncthreads();  /* h0[PA] visible */                                \
        if (role == 1) {                                                      \
            MM_F(a, HBASE(PA, 0) + aoff,      0);                             \
            MM(a, HBASE(PA, 0) + aoff + 32, 1);                               \
            MM(a, HBASE(PA, 1) + aoff,      2);                               \
            MM(a, HBASE(PA, 1) + aoff + 32, 3);                               \
            CELL(a, 1, 1 - (PA));                                             \
        }                                                                     \
        __syncthreads();  /* h1[1-PA] visible */                              \
        if (role == 2) {                                                      \
            MM_F(a, HBASE(1 - (PA), 1) + aoff,      0);                       \
            MM(a, HBASE(1 - (PA), 1) + aoff + 32, 1);                         \
            MM(a, HBASE(1 - (PA), 2) + aoff,      2);                         \
            MM(a, HBASE(1 - (PA), 2) + aoff + 32, 3);                         \
            CELL(a, 2, PA);                                                   \
        }                                                                     \
        __syncthreads();  /* h2[PA] visible */                                \
        if (role == 0) {                                                      \
            float sm = 0.f, sa = 0.f;                                         \
            const f16* h2p = HBASE(PA, 2) + mH * HSTR;                        \
            _Pragma("unroll")                                                 \
            for (int r = 0; r < 4; ++r) {                                     \
                float hv = (float)h2p[(tid & 15) + 16 * r];                   \
                sm += hv * wmr[r];                                            \
                sa += hv * war[r];                                            \
            }                                                                 \
            _Pragma("unroll")                                                 \
            for (int off = 1; off < 16; off <<= 1) {                          \
                sm += __shfl_xor(sm, off, 64);                                \
                sa += __shfl_xor(sa, off, 64);                                \
            }                                                                 \
            if ((tid & 15) == 0) {                                            \
                float mo  = (sm + bmv) * vf;                                  \
                float ao  = softplusf(sa + bav) * vf;                         \
                float zsv = mo + ao * eps[(size_t)(bg + mH) * TD + (t)];      \
                out[(size_t)(bg + mH) * TD + (t)] = zsv;                      \
                zbuf[mH] = zsv / vf;                                          \
            }                                                                 \
        }                                                                     \
    }

    for (int t = 0; t < TD; t += 2) {
        DEC_STEP(0, t)
        DEC_STEP(1, t + 1)
    }

#undef HBASE
#undef MFMA16
#undef MM_F
#undef MM
#undef CELL
#undef ROUND
#undef DEC_STEP
}

extern "C" void kernel_launch(void* const* d_in, const int* in_sizes, int n_in,
                              void* d_out, int out_size, void* d_ws, size_t ws_size,
                              hipStream_t stream) {
    const float* enc_x = (const float*)d_in[0];
    const float* enc_z = (const float*)d_in[1];
    const float* dec_x = (const float*)d_in[2];
    const float* v     = (const float*)d_in[3];
    const float* eps   = (const float*)d_in[4];
    const float* Wih0  = (const float*)d_in[5];
    const float* Whh0  = (const float*)d_in[6];
    const float* b0    = (const float*)d_in[7];
    const float* Wih1  = (const float*)d_in[8];
    const float* Whh1  = (const float*)d_in[9];
    const float* b1    = (const float*)d_in[10];
    const float* Wih2  = (const float*)d_in[11];
    const float* Whh2  = (const float*)d_in[12];
    const float* b2    = (const float*)d_in[13];
    const float* w_m   = (const float*)d_in[14];
    const float* b_m   = (const float*)d_in[15];
    const float* w_a   = (const float*)d_in[16];
    const float* b_a   = (const float*)d_in[17];
    float* out = (float*)d_out;
    f16*   pk  = (f16*)d_ws;

    pack_kernel<<<384, 256, 0, stream>>>(Wih0, Whh0, Wih1, Whh1, Wih2, Whh2, pk);
    lstm_kernel<<<NWG, 768, 0, stream>>>(enc_x, enc_z, dec_x, v, eps, pk,
                                         b0, b1, b2, w_m, b_m, w_a, b_a, out);
}

// Round 8
// 309.860 us; speedup vs baseline: 4.1341x; 4.1341x over previous
//
#include <hip/hip_runtime.h>
#include <math.h>

#define B_TOT 4096
#define TE 168
#define TD 24
#define NWG 256          // 16 batches per WG; 768 threads -> 3 waves/SIMD
#define HSTR 72          // padded f16 row stride (144 B, 16B-aligned)

typedef _Float16 f16;
typedef __attribute__((ext_vector_type(8))) _Float16 f16x8;
typedef __attribute__((ext_vector_type(4))) float f32x4;

// Activation pre-scaling folded into weights/biases:
//   i,f,o: w *= -log2(e)  -> E = exp2(y) = e^{-x}; sigmoid = 1/(1+E)
//   g:     w *= 2*log2(e) -> E = e^{2x};  tanh = (E-1)/(E+1)
#define SCL_S (-1.4426950408889634f)
#define SCL_G (2.885390081777927f)

// ---------------------------------------------------------------------------
// Pack weights into MFMA B-fragment order, f16, pre-scaled per gate:
//   pk[w][l][q][c][lane][j] = scale_q * Wcomb_l[q*64+w*16+(lane&15)][c*32+(lane>>4)*8+j]
//   l=0 (K=96):  k<8 -> Wih0; 8..31 -> 0; 32..95 -> Whh0[k-32]  (c=3 all zero)
//   l=1 (K=128): k<64 -> Wih1 (input h0); else Whh1[k-64] (recurrent h1)
//   l=2 (K=128): k<64 -> Wih2 (input h1); else Whh2[k-64] (recurrent h2)
// ---------------------------------------------------------------------------
__global__ __launch_bounds__(256) void pack_kernel(
    const float* __restrict__ Wih0, const float* __restrict__ Whh0,
    const float* __restrict__ Wih1, const float* __restrict__ Whh1,
    const float* __restrict__ Wih2, const float* __restrict__ Whh2,
    f16* __restrict__ pk)
{
    int idx = blockIdx.x * 256 + threadIdx.x;   // 0 .. 98303
    int j = idx & 7;
    int t = idx >> 3;
    int ln = t & 63; t >>= 6;
    int c  = t & 3;  t >>= 2;
    int q  = t & 3;  t >>= 2;
    int l  = t % 3;
    int w  = t / 3;
    int row = q * 64 + w * 16 + (ln & 15);
    int k   = c * 32 + ((ln >> 4) << 3) + j;
    float val = 0.f;
    if (l == 0) {
        if (k < 8)                 val = Wih0[row * 8 + k];
        else if (k >= 32 && k < 96) val = Whh0[row * 64 + (k - 32)];
    } else if (l == 1) {
        val = (k < 64) ? Wih1[row * 64 + k] : Whh1[row * 64 + (k - 64)];
    } else {
        val = (k < 64) ? Wih2[row * 64 + k] : Whh2[row * 64 + (k - 64)];
    }
    const float sc = (q == 2) ? SCL_G : SCL_S;
    pk[idx] = (f16)(val * sc);
}

__device__ __forceinline__ float softplusf(float x) { return fmaxf(x, 0.f) + log1pf(__expf(-fabsf(x))); }

// ---------------------------------------------------------------------------
// 256 WGs x 768 threads (12 waves); WG owns 16 batches (M=16 tile dense).
// One LAYER per wave role: role = tid>>8 -> 0:L0, 1:L1, 2:L2+staging; within
// a role, wave wv owns hid block wv*16..+16. Per SIMD: 3 balanced independent
// issue streams. Encoder layer-pipelined: round r computes L0(t), L1(t-1),
// L2(t-2); reads parity 1-pp, writes pp; ONE barrier per round.
// R7 BUG FIXED: weight-load loop had runtime trip count (nch) -> wgt demoted
// to scratch (VGPR=64, FETCH 4.2 GB). Now fully unrolled, compile-time
// indices only -> register-resident.
// ---------------------------------------------------------------------------
__global__ __launch_bounds__(768, 3) void lstm_kernel(
    const float* __restrict__ enc_x, const float* __restrict__ enc_z,
    const float* __restrict__ dec_x, const float* __restrict__ v,
    const float* __restrict__ eps,   const f16* __restrict__ pk,
    const float* __restrict__ b0, const float* __restrict__ b1,
    const float* __restrict__ b2,
    const float* __restrict__ w_m, const float* __restrict__ b_m,
    const float* __restrict__ w_a, const float* __restrict__ b_a,
    float* __restrict__ out)
{
    const int tid  = threadIdx.x;
    const int lane = tid & 63;
    const int wv   = (tid >> 6) & 3;    // hid block within role
    const int role = tid >> 8;          // 0:L0, 1:L1, 2:L2+staging
    const int bg   = blockIdx.x * 16;
    const int m16  = lane & 15;
    const int quad = lane >> 4;

    __shared__ f16  hbuf[2][3][16][HSTR];   // [parity][layer][batch][hid]
    __shared__ f16  xbuf[2][16][32];        // [parity][batch][k] (k>=8 stays 0)
    __shared__ float zbuf[16];

    // ---- zero LDS ----
    {
        uint* hz = (uint*)&hbuf[0][0][0][0];
        const int HW = 2 * 3 * 16 * HSTR / 2;   // 3456 words
        for (int i = tid; i < HW; i += 768) hz[i] = 0u;
        uint* xz = (uint*)&xbuf[0][0][0];
        for (int i = tid; i < 512; i += 768) xz[i] = 0u;
    }

    // ---- weight fragments: this wave's layer only. FULLY UNROLLED,
    //      compile-time indices -> guaranteed register-resident. ----
    f16x8 wgt[4][4];                    // [chunk][gate]
#define PKOFF(l, q, c) ((((((size_t)wv * 3 + (l)) * 4 + (q)) * 4 + (c)) * 64 + lane) * 8)
    {
        const f16* pkr = pk + PKOFF(role, 0, 0);
#pragma unroll
        for (int q = 0; q < 4; ++q)
#pragma unroll
            for (int c = 0; c < 4; ++c)
                wgt[c][q] = *(const f16x8*)(pkr + (q * 4 + c) * 64 * 8);
    }
#undef PKOFF

    const int hid_self = wv * 16 + m16;
    // bias splats (pre-scaled) for this wave's layer; MFMA C operand
    f32x4 bsp[4];
    {
        const float* bp = (role == 0) ? b0 : (role == 1) ? b1 : b2;
#pragma unroll
        for (int q = 0; q < 4; ++q) {
            const float sc = (q == 2) ? SCL_G : SCL_S;
            float bv = bp[q * 64 + hid_self] * sc;
            bsp[q] = (f32x4){bv, bv, bv, bv};
        }
    }

    f16* hb = &hbuf[0][0][0][0];
    const int aoff = m16 * HSTR + quad * 8;
    float cst[4] = {};                  // cell state for this wave's layer

#define HBASE(pp, l) (hb + ((pp) * 3 + (l)) * (16 * HSTR))
#define MFMA16(af, bf, cf) __builtin_amdgcn_mfma_f32_16x16x32_f16(af, bf, cf, 0, 0, 0)

#define MM_F(P, aptr, wi)                                                     \
    {                                                                         \
        f16x8 af = *(const f16x8*)(aptr);                                     \
        P##0 = MFMA16(af, wgt[wi][0], bsp[0]);                                \
        P##1 = MFMA16(af, wgt[wi][1], bsp[1]);                                \
        P##2 = MFMA16(af, wgt[wi][2], bsp[2]);                                \
        P##3 = MFMA16(af, wgt[wi][3], bsp[3]);                                \
    }
#define MM(P, aptr, wi)                                                       \
    {                                                                         \
        f16x8 af = *(const f16x8*)(aptr);                                     \
        P##0 = MFMA16(af, wgt[wi][0], P##0);                                  \
        P##1 = MFMA16(af, wgt[wi][1], P##1);                                  \
        P##2 = MFMA16(af, wgt[wi][2], P##2);                                  \
        P##3 = MFMA16(af, wgt[wi][3], P##3);                                  \
    }

// Merged-rcp cell: sigmoid(f)=pig*R, i*g=(Eg-1)*ef1*R, R=rcp(pig*ef1);
// o*tanh(c)=(Ec-1)*rcp((1+Eo)(1+Ec)). 5 exp2 + 2 rcp per output.
// C/D layout (m89): lane -> col(hid)=m16, rows(batch)=quad*4+r.
#define CELL(P, lh, PP)                                                       \
    {                                                                         \
        f16* hw = HBASE(PP, lh) + hid_self;                                   \
        _Pragma("unroll")                                                     \
        for (int r = 0; r < 4; ++r) {                                         \
            float Ei = __builtin_amdgcn_exp2f(P##0[r]);                       \
            float Ef = __builtin_amdgcn_exp2f(P##1[r]);                       \
            float Eg = __builtin_amdgcn_exp2f(P##2[r]);                       \
            float Eo = __builtin_amdgcn_exp2f(P##3[r]);                       \
            float ef1 = 1.f + Ef;                                             \
            float pig = (1.f + Ei) * (1.f + Eg);                              \
            float R   = __builtin_amdgcn_rcpf(pig * ef1);                     \
            float fv  = pig * R;                                              \
            float ig  = (Eg - 1.f) * ef1 * R;                                 \
            float cn  = fmaf(fv, cst[r], ig);                                 \
            cst[r] = cn;                                                      \
            float Ec  = __builtin_amdgcn_exp2f(cn * SCL_G);                   \
            float Roc = __builtin_amdgcn_rcpf((1.f + Eo) * (1.f + Ec));       \
            hw[(quad * 4 + r) * HSTR] = (f16)((Ec - 1.f) * Roc);              \
        }                                                                     \
    }

    // staging: role-2 threads 512..639 cover 16 batches x 8 k
    const int  sidx = tid - 512;
    const bool isst = (sidx >= 0) && (sidx < 128);
    const int  mS = (sidx >> 3) & 15, kS = sidx & 7;
    const float* xrow = enc_x + ((size_t)(bg + mS) * TE) * 8 + kS;

// One pipelined encoder round, parity PP. role0: L0(t); role1: L1(t-1);
// role2: L2(t-2) + stage x(T0+1) into xbuf[1-PP] (DS), prefetch x(T0+2) (DP).
#define ROUND(PP, D0, D1, D2, DS, DP, T0)                                     \
    {                                                                         \
        __syncthreads();                                                      \
        f32x4 a0, a1, a2, a3;                                                 \
        if (role == 0) {                                                      \
            if (D0) {                                                         \
                MM_F(a, &xbuf[PP][0][0] + m16 * 32 + quad * 8, 0);            \
                MM(a, HBASE(1 - (PP), 0) + aoff,      1);                     \
                MM(a, HBASE(1 - (PP), 0) + aoff + 32, 2);                     \
                CELL(a, 0, PP);                                               \
            }                                                                 \
        } else if (role == 1) {                                               \
            if (D1) {                                                         \
                MM_F(a, HBASE(1 - (PP), 0) + aoff,      0);                   \
                MM(a, HBASE(1 - (PP), 0) + aoff + 32, 1);                     \
                MM(a, HBASE(1 - (PP), 1) + aoff,      2);                     \
                MM(a, HBASE(1 - (PP), 1) + aoff + 32, 3);                     \
                CELL(a, 1, PP);                                               \
            }                                                                 \
        } else {                                                              \
            if (D2) {                                                         \
                MM_F(a, HBASE(1 - (PP), 1) + aoff,      0);                   \
                MM(a, HBASE(1 - (PP), 1) + aoff + 32, 1);                     \
                MM(a, HBASE(1 - (PP), 2) + aoff,      2);                     \
                MM(a, HBASE(1 - (PP), 2) + aoff + 32, 3);                     \
            }                                                                 \
            if (DS && isst) {                                                 \
                xbuf[1 - (PP)][mS][kS] = (f16)xpre;                           \
                if (DP) xpre = xrow[((T0) + 2) * 8];                          \
            }                                                                 \
            if (D2) CELL(a, 2, PP);                                           \
        }                                                                     \
    }

    __syncthreads();   // zero-init visible

    // ---------------- encoder (layer-pipelined) ----------------
    float xpre = 0.f;
    if (isst) {
        xbuf[0][mS][kS] = (f16)xrow[0];
        xpre = xrow[8];
    }
    ROUND(0, 1, 0, 0, 1, 1, 0)           // r=0: L0(0)
    ROUND(1, 1, 1, 0, 1, 1, 1)           // r=1: L0(1), L1(0)
    for (int t = 2; t < 166; t += 2) {   // rounds 2..165 dense
        ROUND(0, 1, 1, 1, 1, 1, t)
        ROUND(1, 1, 1, 1, 1, 1, t + 1)
    }
    ROUND(0, 1, 1, 1, 1, 0, 166)         // r=166: stage x(167), no prefetch
    ROUND(1, 1, 1, 1, 0, 0, 167)         // r=167: last L0
    ROUND(0, 0, 1, 1, 0, 0, 168)         // r=168: L1(167), L2(166)
    ROUND(1, 0, 0, 1, 0, 0, 169)         // r=169: L2(167)
    // exit parities: h0(167)->buf1, h1(167)->buf0, h2(167)->buf1

    // ---------------- decoder (serial; z feedback) ----------------
    const int   mH = (tid >> 4) & 15;     // head batch (role 0, 16 thr each)
    const float vf = (role == 0) ? v[bg + mH] : 0.f;
    float wmr[4], war[4];
#pragma unroll
    for (int r = 0; r < 4; ++r) {
        wmr[r] = w_m[(tid & 15) + 16 * r];
        war[r] = w_a[(tid & 15) + 16 * r];
    }
    const float bmv = b_m[0], bav = b_a[0];
    if (role == 0 && (tid & 15) == 0)
        zbuf[mH] = enc_z[(size_t)(bg + mH) * TE + (TE - 1)] / vf;

// Parities per step t (PA = t&1): L0 reads h0[1-PA] writes h0[PA];
// L1 reads h0[PA]+h1[PA] writes h1[1-PA]; L2 reads h1[1-PA]+h2[1-PA]
// writes h2[PA]; head reads h2[PA]. Matches encoder exit at t=0 (PA=0).
#define DEC_STEP(PA, t)                                                       \
    {                                                                         \
        __syncthreads();  /* zbuf + prev h visible */                         \
        if (isst) {                                                           \
            float xv = (kS == 0) ? zbuf[mS]                                   \
                                 : dec_x[((size_t)(bg + mS) * TD + (t)) * 7 + (kS - 1)]; \
            xbuf[PA][mS][kS] = (f16)xv;                                       \
        }                                                                     \
        __syncthreads();  /* x visible */                                     \
        f32x4 a0, a1, a2, a3;                                                 \
        if (role == 0) {                                                      \
            MM_F(a, &xbuf[PA][0][0] + m16 * 32 + quad * 8, 0);                \
            MM(a, HBASE(1 - (PA), 0) + aoff,      1);                         \
            MM(a, HBASE(1 - (PA), 0) + aoff + 32, 2);                         \
            CELL(a, 0, PA);                                                   \
        }                                                                     \
        __syncthreads();  /* h0[PA] visible */                                \
        if (role == 1) {                                                      \
            MM_F(a, HBASE(PA, 0) + aoff,      0);                             \
            MM(a, HBASE(PA, 0) + aoff + 32, 1);                               \
            MM(a, HBASE(PA, 1) + aoff,      2);                               \
            MM(a, HBASE(PA, 1) + aoff + 32, 3);                               \
            CELL(a, 1, 1 - (PA));                                             \
        }                                                                     \
        __syncthreads();  /* h1[1-PA] visible */                              \
        if (role == 2) {                                                      \
            MM_F(a, HBASE(1 - (PA), 1) + aoff,      0);                       \
            MM(a, HBASE(1 - (PA), 1) + aoff + 32, 1);                         \
            MM(a, HBASE(1 - (PA), 2) + aoff,      2);                         \
            MM(a, HBASE(1 - (PA), 2) + aoff + 32, 3);                         \
            CELL(a, 2, PA);                                                   \
        }                                                                     \
        __syncthreads();  /* h2[PA] visible */                                \
        if (role == 0) {                                                      \
            float sm = 0.f, sa = 0.f;                                         \
            const f16* h2p = HBASE(PA, 2) + mH * HSTR;                        \
            _Pragma("unroll")                                                 \
            for (int r = 0; r < 4; ++r) {                                     \
                float hv = (float)h2p[(tid & 15) + 16 * r];                   \
                sm += hv * wmr[r];                                            \
                sa += hv * war[r];                                            \
            }                                                                 \
            _Pragma("unroll")                                                 \
            for (int off = 1; off < 16; off <<= 1) {                          \
                sm += __shfl_xor(sm, off, 64);                                \
                sa += __shfl_xor(sa, off, 64);                                \
            }                                                                 \
            if ((tid & 15) == 0) {                                            \
                float mo  = (sm + bmv) * vf;                                  \
                float ao  = softplusf(sa + bav) * vf;                         \
                float zsv = mo + ao * eps[(size_t)(bg + mH) * TD + (t)];      \
                out[(size_t)(bg + mH) * TD + (t)] = zsv;                      \
                zbuf[mH] = zsv / vf;                                          \
            }                                                                 \
        }                                                                     \
    }

    for (int t = 0; t < TD; t += 2) {
        DEC_STEP(0, t)
        DEC_STEP(1, t + 1)
    }

#undef HBASE
#undef MFMA16
#undef MM_F
#undef MM
#undef CELL
#undef ROUND
#undef DEC_STEP
}

extern "C" void kernel_launch(void* const* d_in, const int* in_sizes, int n_in,
                              void* d_out, int out_size, void* d_ws, size_t ws_size,
                              hipStream_t stream) {
    const float* enc_x = (const float*)d_in[0];
    const float* enc_z = (const float*)d_in[1];
    const float* dec_x = (const float*)d_in[2];
    const float* v     = (const float*)d_in[3];
    const float* eps   = (const float*)d_in[4];
    const float* Wih0  = (const float*)d_in[5];
    const float* Whh0  = (const float*)d_in[6];
    const float* b0    = (const float*)d_in[7];
    const float* Wih1  = (const float*)d_in[8];
    const float* Whh1  = (const float*)d_in[9];
    const float* b1    = (const float*)d_in[10];
    const float* Wih2  = (const float*)d_in[11];
    const float* Whh2  = (const float*)d_in[12];
    const float* b2    = (const float*)d_in[13];
    const float* w_m   = (const float*)d_in[14];
    const float* b_m   = (const float*)d_in[15];
    const float* w_a   = (const float*)d_in[16];
    const float* b_a   = (const float*)d_in[17];
    float* out = (float*)d_out;
    f16*   pk  = (f16*)d_ws;

    pack_kernel<<<384, 256, 0, stream>>>(Wih0, Whh0, Wih1, Whh1, Wih2, Whh2, pk);
    lstm_kernel<<<NWG, 768, 0, stream>>>(enc_x, enc_z, dec_x, v, eps, pk,
                                         b0, b1, b2, w_m, b_m, w_a, b_a, out);
}